// Round 5
// baseline (290.444 us; speedup 1.0000x reference)
//
#include <hip/hip_runtime.h>

#define D_FEAT 96
#define P_DIM 96
#define OUT_DIM 192
#define SCAN_BLK 256
#define NODES_PER_BLK 8
#define LPN 24        // lanes per node: 24 x float4 = 96 floats
#define NPB 64        // nodes per sort bucket (power of 2)
#define NPB_SHIFT 6

typedef float f32x4 __attribute__((ext_vector_type(4)));

// ---------------- fallback (round-1) kernels: used only if ws too small ----
__global__ __launch_bounds__(256) void zero_k(float* __restrict__ out,
                                              float* __restrict__ deg,
                                              int n_out, int n_deg) {
    int stride = gridDim.x * blockDim.x;
    for (int i = blockIdx.x * blockDim.x + threadIdx.x; i < n_out; i += stride)
        out[i] = 0.0f;
    for (int i = blockIdx.x * blockDim.x + threadIdx.x; i < n_deg; i += stride)
        deg[i] = 0.0f;
}

__global__ __launch_bounds__(256) void degf_k(const int* __restrict__ dst,
                                              float* __restrict__ deg,
                                              int n_edges) {
    int e = blockIdx.x * blockDim.x + threadIdx.x;
    if (e < n_edges) atomicAdd(deg + dst[e], 1.0f);
}

__global__ __launch_bounds__(256) void scatter_k(const float* __restrict__ emb,
                                                 const int* __restrict__ src,
                                                 const int* __restrict__ dst,
                                                 float* __restrict__ out,
                                                 int n_edges) {
    int idx = blockIdx.x * blockDim.x + threadIdx.x;
    int e = idx / D_FEAT;
    if (e >= n_edges) return;
    int c = idx - e * D_FEAT;
    atomicAdd(out + (size_t)dst[e] * OUT_DIM + c, emb[(size_t)src[e] * D_FEAT + c]);
}

__global__ __launch_bounds__(256) void prompt_k(const float* __restrict__ w,
                                                const float* __restrict__ deg,
                                                float* __restrict__ out,
                                                int n_nodes) {
    int idx = blockIdx.x * blockDim.x + threadIdx.x;
    if (idx >= n_nodes * P_DIM) return;
    int v = idx / P_DIM;
    int c = idx - v * P_DIM;
    out[(size_t)v * OUT_DIM + P_DIM + c] = deg[v] * w[c];
}

// ---------------- sorted-CSR path ------------------------------------------

// hist[dst[e]]++
__global__ __launch_bounds__(256) void hist_k(const int* __restrict__ dst,
                                              int* __restrict__ hist, int n_edges) {
    int e = blockIdx.x * blockDim.x + threadIdx.x;
    if (e < n_edges) atomicAdd(hist + dst[e], 1);
}

// per-block exclusive scan; aux[b] = block sum
__global__ __launch_bounds__(SCAN_BLK) void scan_block_k(const int* __restrict__ hist,
                                                         int* __restrict__ offs,
                                                         int* __restrict__ aux, int n) {
    __shared__ int buf[SCAN_BLK];
    int t = threadIdx.x;
    int i = blockIdx.x * SCAN_BLK + t;
    int v = (i < n) ? hist[i] : 0;
    buf[t] = v;
    __syncthreads();
    for (int off = 1; off < SCAN_BLK; off <<= 1) {
        int x = (t >= off) ? buf[t - off] : 0;
        __syncthreads();
        buf[t] += x;
        __syncthreads();
    }
    if (i < n) offs[i] = buf[t] - v;          // exclusive within block
    if (t == SCAN_BLK - 1) aux[blockIdx.x] = buf[t];
}

// each block redundantly scans aux[nb] in LDS, adds its base to offs
__global__ __launch_bounds__(SCAN_BLK) void scan_add_k(int* __restrict__ offs,
                                                       const int* __restrict__ aux,
                                                       int n, int nb) {
    __shared__ int buf[SCAN_BLK];
    int t = threadIdx.x;
    buf[t] = (t < nb) ? aux[t] : 0;
    __syncthreads();
    for (int off = 1; off < SCAN_BLK; off <<= 1) {    // inclusive scan
        int x = (t >= off) ? buf[t - off] : 0;
        __syncthreads();
        buf[t] += x;
        __syncthreads();
    }
    int base = (blockIdx.x == 0) ? 0 : buf[blockIdx.x - 1];
    int i = blockIdx.x * SCAN_BLK + t;
    if (i < n) offs[i] += base;
}

// bucket cursors = CSR offset of each bucket's first node
__global__ __launch_bounds__(256) void bcur_k(const int* __restrict__ offs,
                                              int* __restrict__ bcur, int n_buckets) {
    int b = blockIdx.x * blockDim.x + threadIdx.x;
    if (b < n_buckets) bcur[b] = offs[b << NPB_SHIFT];
}

// phase A: scatter packed (src<<6 | dst&63) into the bucket's CSR region.
// ~800 active cursors -> partially-filled lines stay L2-resident.
__global__ __launch_bounds__(256) void bucketA_k(const int* __restrict__ src,
                                                 const int* __restrict__ dst,
                                                 int* __restrict__ bcur,
                                                 int* __restrict__ pack,
                                                 int n_edges) {
    int e = blockIdx.x * blockDim.x + threadIdx.x;
    if (e < n_edges) {
        int d = dst[e];
        int pos = atomicAdd(bcur + (d >> NPB_SHIFT), 1);
        pack[pos] = (src[e] << NPB_SHIFT) | (d & (NPB - 1));
    }
}

// phase B: one block per bucket; LDS cursors; writes land in the bucket's own
// contiguous CSR window (~few KB) -> lines fill before eviction.
__global__ __launch_bounds__(256) void bucketB_k(const int* __restrict__ pack,
                                                 const int* __restrict__ offs,
                                                 int* __restrict__ sorted_src,
                                                 int n_nodes, int n_edges) {
    __shared__ int cur[NPB];
    int b = blockIdx.x;
    int base_node = b << NPB_SHIFT;
    int t = threadIdx.x;
    if (t < NPB) {
        int nidx = base_node + t;
        cur[t] = (nidx < n_nodes) ? offs[nidx] : n_edges;
    }
    __syncthreads();
    int start = offs[base_node];
    int end_node = base_node + NPB;
    int end = (end_node < n_nodes) ? offs[end_node] : n_edges;
    for (int i = start + t; i < end; i += 256) {
        int p = pack[i];
        int pos = atomicAdd(&cur[p & (NPB - 1)], 1);
        sorted_src[pos] = p >> NPB_SHIFT;
    }
}

// one node per 24 lanes, float4 gathers, 4-way unroll (64B in flight/thread)
__global__ __launch_bounds__(NODES_PER_BLK * LPN) void agg4_k(
        const f32x4* __restrict__ emb4,      // [N, 24] f32x4
        const f32x4* __restrict__ w4,        // [24] f32x4
        const int* __restrict__ offs,
        const int* __restrict__ hist,
        const int* __restrict__ sorted_src,
        float* __restrict__ out, int n_nodes) {
    int t = threadIdx.x;
    int sub = t / LPN;
    int lane = t - sub * LPN;                 // float4 column index 0..23
    int node = blockIdx.x * NODES_PER_BLK + sub;
    if (node >= n_nodes) return;

    int start = offs[node];
    int cnt = hist[node];

    f32x4 a0 = {0.f, 0.f, 0.f, 0.f};
    f32x4 a1 = a0, a2 = a0, a3 = a0;
    int j = 0;
    for (; j + 3 < cnt; j += 4) {
        int s0 = sorted_src[start + j];
        int s1 = sorted_src[start + j + 1];
        int s2 = sorted_src[start + j + 2];
        int s3 = sorted_src[start + j + 3];
        f32x4 v0 = emb4[(size_t)s0 * LPN + lane];
        f32x4 v1 = emb4[(size_t)s1 * LPN + lane];
        f32x4 v2 = emb4[(size_t)s2 * LPN + lane];
        f32x4 v3 = emb4[(size_t)s3 * LPN + lane];
        a0 += v0; a1 += v1; a2 += v2; a3 += v3;
    }
    for (; j < cnt; ++j) {
        int s0 = sorted_src[start + j];
        a0 += emb4[(size_t)s0 * LPN + lane];
    }
    f32x4 ft = (a0 + a1) + (a2 + a3);

    f32x4* outrow = (f32x4*)(out + (size_t)node * OUT_DIM);
    float c = (float)cnt;
    f32x4 pv = c * w4[lane];
    __builtin_nontemporal_store(ft, outrow + lane);
    __builtin_nontemporal_store(pv, outrow + LPN + lane);
}

extern "C" void kernel_launch(void* const* d_in, const int* in_sizes, int n_in,
                              void* d_out, int out_size, void* d_ws, size_t ws_size,
                              hipStream_t stream) {
    const float* emb = (const float*)d_in[0];   // [N, 96] f32
    const float* w   = (const float*)d_in[1];   // [1, 96] f32
    const int*   src = (const int*)d_in[2];     // [E] int32
    const int*   dst = (const int*)d_in[3];     // [E] int32
    float* out = (float*)d_out;                 // [N, 192] f32

    const int n_nodes = in_sizes[0] / D_FEAT;
    const int n_edges = in_sizes[2];
    const int nb = (n_nodes + SCAN_BLK - 1) / SCAN_BLK;
    const int n_buckets = (n_nodes + NPB - 1) / NPB;

    // ws layout (int32): hist[N] | offs[N] | aux[SCAN_BLK] | bcur[NB] | pack[E] | sorted_src[E]
    size_t need = ((size_t)2 * n_nodes + SCAN_BLK + n_buckets + 2 * (size_t)n_edges) * sizeof(int);
    bool can_pack = n_nodes <= (1 << (31 - NPB_SHIFT));

    if (ws_size < need || nb > SCAN_BLK || !can_pack) {
        // fallback: round-1 atomic path (correct, slower)
        float* deg = (float*)d_ws;
        int n_out = n_nodes * OUT_DIM;
        int blocks = (n_out + 255) / 256;
        if (blocks > 2048) blocks = 2048;
        zero_k<<<blocks, 256, 0, stream>>>(out, deg, n_out, n_nodes);
        degf_k<<<(n_edges + 255) / 256, 256, 0, stream>>>(dst, deg, n_edges);
        long long total = (long long)n_edges * D_FEAT;
        scatter_k<<<(int)((total + 255) / 256), 256, 0, stream>>>(emb, src, dst, out, n_edges);
        prompt_k<<<(n_nodes * P_DIM + 255) / 256, 256, 0, stream>>>(w, deg, out, n_nodes);
        return;
    }

    int* hist       = (int*)d_ws;
    int* offs       = hist + n_nodes;
    int* aux        = offs + n_nodes;
    int* bcur       = aux + SCAN_BLK;
    int* pack       = bcur + n_buckets;
    int* sorted_src = pack + n_edges;

    (void)hipMemsetAsync(hist, 0, (size_t)n_nodes * sizeof(int), stream);
    hist_k<<<(n_edges + 255) / 256, 256, 0, stream>>>(dst, hist, n_edges);
    scan_block_k<<<nb, SCAN_BLK, 0, stream>>>(hist, offs, aux, n_nodes);
    scan_add_k<<<nb, SCAN_BLK, 0, stream>>>(offs, aux, n_nodes, nb);
    bcur_k<<<(n_buckets + 255) / 256, 256, 0, stream>>>(offs, bcur, n_buckets);
    bucketA_k<<<(n_edges + 255) / 256, 256, 0, stream>>>(src, dst, bcur, pack, n_edges);
    bucketB_k<<<n_buckets, 256, 0, stream>>>(pack, offs, sorted_src, n_nodes, n_edges);
    agg4_k<<<(n_nodes + NODES_PER_BLK - 1) / NODES_PER_BLK, NODES_PER_BLK * LPN, 0, stream>>>(
        (const f32x4*)emb, (const f32x4*)w, offs, hist, sorted_src, out, n_nodes);
}

// Round 6
// 80.131 us; speedup vs baseline: 3.6246x; 3.6246x over previous
//
#include <hip/hip_runtime.h>

#define D_FEAT 96
#define P_DIM 96
#define OUT_DIM 192
#define SCAN_BLK 256
#define NODES_PER_BLK 8
#define LPN 24          // lanes per node: 24 x float4 = 96 floats
#define RNG_SHIFT 8     // 256 nodes per range
#define RNG_NODES 256
#define NBLK_A 256      // binning blocks (fixed; chunk derived)

typedef float f32x4 __attribute__((ext_vector_type(4)));

// ---------------- fallback (round-1) kernels: used only if ws too small ----
__global__ __launch_bounds__(256) void zero_k(float* __restrict__ out,
                                              float* __restrict__ deg,
                                              int n_out, int n_deg) {
    int stride = gridDim.x * blockDim.x;
    for (int i = blockIdx.x * blockDim.x + threadIdx.x; i < n_out; i += stride)
        out[i] = 0.0f;
    for (int i = blockIdx.x * blockDim.x + threadIdx.x; i < n_deg; i += stride)
        deg[i] = 0.0f;
}

__global__ __launch_bounds__(256) void degf_k(const int* __restrict__ dst,
                                              float* __restrict__ deg,
                                              int n_edges) {
    int e = blockIdx.x * blockDim.x + threadIdx.x;
    if (e < n_edges) atomicAdd(deg + dst[e], 1.0f);
}

__global__ __launch_bounds__(256) void scatter_k(const float* __restrict__ emb,
                                                 const int* __restrict__ src,
                                                 const int* __restrict__ dst,
                                                 float* __restrict__ out,
                                                 int n_edges) {
    int idx = blockIdx.x * blockDim.x + threadIdx.x;
    int e = idx / D_FEAT;
    if (e >= n_edges) return;
    int c = idx - e * D_FEAT;
    atomicAdd(out + (size_t)dst[e] * OUT_DIM + c, emb[(size_t)src[e] * D_FEAT + c]);
}

__global__ __launch_bounds__(256) void prompt_k(const float* __restrict__ w,
                                                const float* __restrict__ deg,
                                                float* __restrict__ out,
                                                int n_nodes) {
    int idx = blockIdx.x * blockDim.x + threadIdx.x;
    if (idx >= n_nodes * P_DIM) return;
    int v = idx / P_DIM;
    int c = idx - v * P_DIM;
    out[(size_t)v * OUT_DIM + P_DIM + c] = deg[v] * w[c];
}

// ---------------- deterministic two-pass binned counting sort --------------

// Phase A: per-block LDS histogram over node-ranges.
// cnt[r * NBLK_A + b] = #edges in block b's chunk with dst in range r.
__global__ __launch_bounds__(256) void binhist_k(const int* __restrict__ dst,
                                                 int* __restrict__ cnt,
                                                 int n_edges, int nr, int chunk) {
    __shared__ int h[RNG_NODES];
    int b = blockIdx.x, t = threadIdx.x;
    h[t] = 0;
    __syncthreads();
    int beg = b * chunk;
    int end = beg + chunk; if (end > n_edges) end = n_edges;
    for (int i = beg + t; i < end; i += 256)
        atomicAdd(&h[dst[i] >> RNG_SHIFT], 1);
    __syncthreads();
    if (t < nr) cnt[t * NBLK_A + b] = h[t];
}

// per-block exclusive scan (in-place safe); aux[b] = block sum
__global__ __launch_bounds__(SCAN_BLK) void scan_block_k(const int* __restrict__ in,
                                                         int* __restrict__ outp,
                                                         int* __restrict__ aux, int n) {
    __shared__ int buf[SCAN_BLK];
    int t = threadIdx.x;
    int i = blockIdx.x * SCAN_BLK + t;
    int v = (i < n) ? in[i] : 0;
    buf[t] = v;
    __syncthreads();
    for (int off = 1; off < SCAN_BLK; off <<= 1) {
        int x = (t >= off) ? buf[t - off] : 0;
        __syncthreads();
        buf[t] += x;
        __syncthreads();
    }
    if (i < n) outp[i] = buf[t] - v;          // exclusive within block
    if (t == SCAN_BLK - 1) aux[blockIdx.x] = buf[t];
}

// each block redundantly scans aux[nb] in LDS, adds its base
__global__ __launch_bounds__(SCAN_BLK) void scan_add_k(int* __restrict__ arr,
                                                       const int* __restrict__ aux,
                                                       int n, int nb) {
    __shared__ int buf[SCAN_BLK];
    int t = threadIdx.x;
    buf[t] = (t < nb) ? aux[t] : 0;
    __syncthreads();
    for (int off = 1; off < SCAN_BLK; off <<= 1) {    // inclusive scan
        int x = (t >= off) ? buf[t - off] : 0;
        __syncthreads();
        buf[t] += x;
        __syncthreads();
    }
    int base = (blockIdx.x == 0) ? 0 : buf[blockIdx.x - 1];
    int i = blockIdx.x * SCAN_BLK + t;
    if (i < n) arr[i] += base;
}

// Phase C: re-read chunk; append packed (src<<8 | dst&255) into this block's
// private slice of each range region. Sequential per-stream writes fill lines.
// No global atomics.
__global__ __launch_bounds__(256) void binwrite_k(const int* __restrict__ src,
                                                  const int* __restrict__ dst,
                                                  const int* __restrict__ cnt,
                                                  int* __restrict__ pack,
                                                  int n_edges, int nr, int chunk) {
    __shared__ int cur[RNG_NODES];
    int b = blockIdx.x, t = threadIdx.x;
    if (t < nr) cur[t] = cnt[t * NBLK_A + b];   // scanned base of (range t, block b)
    __syncthreads();
    int beg = b * chunk;
    int end = beg + chunk; if (end > n_edges) end = n_edges;
    for (int i = beg + t; i < end; i += 256) {
        int d = dst[i];
        int pos = atomicAdd(&cur[d >> RNG_SHIFT], 1);
        pack[pos] = (src[i] << RNG_SHIFT) | (d & (RNG_NODES - 1));
    }
}

// Phase D: one block per range. LDS hist of the range window + LDS scan gives
// node offsets (written to offs[]); place edges into the CSR window (~16KB,
// L2-resident). Replaces the old hist_k + node-level scan.
__global__ __launch_bounds__(256) void finesort_k(const int* __restrict__ cnt,
                                                  const int* __restrict__ pack,
                                                  int* __restrict__ offs,
                                                  int* __restrict__ sorted_src,
                                                  int n_nodes, int n_edges, int nr) {
    __shared__ int h[RNG_NODES];
    __shared__ int cur[RNG_NODES];
    int r = blockIdx.x, t = threadIdx.x;
    int start = cnt[r * NBLK_A];
    int end = (r + 1 < nr) ? cnt[(r + 1) * NBLK_A] : n_edges;

    h[t] = 0;
    __syncthreads();
    for (int i = start + t; i < end; i += 256)
        atomicAdd(&h[pack[i] & (RNG_NODES - 1)], 1);
    __syncthreads();
    int v = h[t];
    // inclusive scan of h in-place
    for (int off = 1; off < RNG_NODES; off <<= 1) {
        int x = (t >= off) ? h[t - off] : 0;
        __syncthreads();
        h[t] += x;
        __syncthreads();
    }
    int o = start + h[t] - v;                 // exclusive prefix -> node offset
    int node = (r << RNG_SHIFT) + t;
    if (node < n_nodes) offs[node] = o;
    cur[t] = o;
    __syncthreads();
    for (int i = start + t; i < end; i += 256) {
        int p = pack[i];
        int pos = atomicAdd(&cur[p & (RNG_NODES - 1)], 1);
        sorted_src[pos] = p >> RNG_SHIFT;
    }
}

// one node per 24 lanes, float4 gathers, 4-way unroll (64B in flight/thread)
__global__ __launch_bounds__(NODES_PER_BLK * LPN) void agg4_k(
        const f32x4* __restrict__ emb4,      // [N, 24] f32x4
        const f32x4* __restrict__ w4,        // [24] f32x4
        const int* __restrict__ offs,
        const int* __restrict__ sorted_src,
        float* __restrict__ out, int n_nodes, int n_edges) {
    int t = threadIdx.x;
    int sub = t / LPN;
    int lane = t - sub * LPN;                 // float4 column index 0..23
    int node = blockIdx.x * NODES_PER_BLK + sub;
    if (node >= n_nodes) return;

    int start = offs[node];
    int endp = (node + 1 < n_nodes) ? offs[node + 1] : n_edges;
    int cnt = endp - start;

    f32x4 a0 = {0.f, 0.f, 0.f, 0.f};
    f32x4 a1 = a0, a2 = a0, a3 = a0;
    int j = 0;
    for (; j + 3 < cnt; j += 4) {
        int s0 = sorted_src[start + j];
        int s1 = sorted_src[start + j + 1];
        int s2 = sorted_src[start + j + 2];
        int s3 = sorted_src[start + j + 3];
        f32x4 v0 = emb4[(size_t)s0 * LPN + lane];
        f32x4 v1 = emb4[(size_t)s1 * LPN + lane];
        f32x4 v2 = emb4[(size_t)s2 * LPN + lane];
        f32x4 v3 = emb4[(size_t)s3 * LPN + lane];
        a0 += v0; a1 += v1; a2 += v2; a3 += v3;
    }
    for (; j < cnt; ++j) {
        int s0 = sorted_src[start + j];
        a0 += emb4[(size_t)s0 * LPN + lane];
    }
    f32x4 ft = (a0 + a1) + (a2 + a3);

    f32x4* outrow = (f32x4*)(out + (size_t)node * OUT_DIM);
    float c = (float)cnt;
    f32x4 pv = c * w4[lane];
    __builtin_nontemporal_store(ft, outrow + lane);
    __builtin_nontemporal_store(pv, outrow + LPN + lane);
}

extern "C" void kernel_launch(void* const* d_in, const int* in_sizes, int n_in,
                              void* d_out, int out_size, void* d_ws, size_t ws_size,
                              hipStream_t stream) {
    const float* emb = (const float*)d_in[0];   // [N, 96] f32
    const float* w   = (const float*)d_in[1];   // [1, 96] f32
    const int*   src = (const int*)d_in[2];     // [E] int32
    const int*   dst = (const int*)d_in[3];     // [E] int32
    float* out = (float*)d_out;                 // [N, 192] f32

    const int n_nodes = in_sizes[0] / D_FEAT;
    const int n_edges = in_sizes[2];
    const int nr = (n_nodes + RNG_NODES - 1) >> RNG_SHIFT;   // node ranges
    const int cnt_len = nr * NBLK_A;
    const int nb_cnt = (cnt_len + SCAN_BLK - 1) / SCAN_BLK;  // == nr
    const int chunk = (n_edges + NBLK_A - 1) / NBLK_A;

    // ws layout (int32): cnt[nr*NBLK_A] | aux[SCAN_BLK] | offs[N] | pack[E] | sorted_src[E]
    size_t need = ((size_t)cnt_len + SCAN_BLK + n_nodes + 2 * (size_t)n_edges) * sizeof(int);
    bool ok = (nr <= RNG_NODES) && (nb_cnt <= SCAN_BLK) &&
              (n_nodes <= (1 << (31 - RNG_SHIFT - 1)));      // src<<8 fits in int31

    if (ws_size < need || !ok) {
        // fallback: round-1 atomic path (correct, slower)
        float* deg = (float*)d_ws;
        int n_out = n_nodes * OUT_DIM;
        int blocks = (n_out + 255) / 256;
        if (blocks > 2048) blocks = 2048;
        zero_k<<<blocks, 256, 0, stream>>>(out, deg, n_out, n_nodes);
        degf_k<<<(n_edges + 255) / 256, 256, 0, stream>>>(dst, deg, n_edges);
        long long total = (long long)n_edges * D_FEAT;
        scatter_k<<<(int)((total + 255) / 256), 256, 0, stream>>>(emb, src, dst, out, n_edges);
        prompt_k<<<(n_nodes * P_DIM + 255) / 256, 256, 0, stream>>>(w, deg, out, n_nodes);
        return;
    }

    int* cnt        = (int*)d_ws;
    int* aux        = cnt + cnt_len;
    int* offs       = aux + SCAN_BLK;
    int* pack       = offs + n_nodes;
    int* sorted_src = pack + n_edges;

    binhist_k<<<NBLK_A, 256, 0, stream>>>(dst, cnt, n_edges, nr, chunk);
    scan_block_k<<<nb_cnt, SCAN_BLK, 0, stream>>>(cnt, cnt, aux, cnt_len);
    scan_add_k<<<nb_cnt, SCAN_BLK, 0, stream>>>(cnt, aux, cnt_len, nb_cnt);
    binwrite_k<<<NBLK_A, 256, 0, stream>>>(src, dst, cnt, pack, n_edges, nr, chunk);
    finesort_k<<<nr, 256, 0, stream>>>(cnt, pack, offs, sorted_src, n_nodes, n_edges, nr);
    agg4_k<<<(n_nodes + NODES_PER_BLK - 1) / NODES_PER_BLK, NODES_PER_BLK * LPN, 0, stream>>>(
        (const f32x4*)emb, (const f32x4*)w, offs, sorted_src, out, n_nodes, n_edges);
}